// Round 14
// baseline (501.004 us; speedup 1.0000x reference)
//
#include <hip/hip_runtime.h>
#include <math.h>
#include <stdint.h>

#define NLV 16
#define NDENSE 6
#define NHASH 10
#define NMERGE 6          // hashed levels 6..11 merged (pass A)
#define NMERGE2 4         // hashed levels 12..15 merged (pass B)
#define SORT_RES 32
#define NBINS (SORT_RES * SORT_RES * SORT_RES)   // 32768

typedef float evf2 __attribute__((ext_vector_type(2)));
typedef float evf4 __attribute__((ext_vector_type(4)));
typedef unsigned int evu4 __attribute__((ext_vector_type(4)));
typedef _Float16 evh2 __attribute__((ext_vector_type(2)));
typedef _Float16 evh4 __attribute__((ext_vector_type(4)));

struct Params {
  float scale[NLV];
  uint32_t res[NLV];
  uint32_t msize[NLV];
  uint32_t offset[NLV];
};

struct ParamsD {
  float scale[NDENSE];
  uint32_t res[NDENSE];
  uint32_t msize[NDENSE];
  uint32_t offset[NDENSE];
};

struct ParamsH {
  float scale[NMERGE];
  uint32_t offset[NMERGE];
};

struct ParamsH2 {
  float scale[NMERGE2];
  uint32_t offset[NMERGE2];
};

// bijective XCD swizzle (m204)
__device__ __forceinline__ int xcd_swz(int bid, int nwg) {
  int q = nwg >> 3, r = nwg & 7;
  int x = bid & 7, i = bid >> 3;
  return (x < r ? x * (q + 1) : r * (q + 1) + (x - r) * q) + i;
}

__device__ __forceinline__ uint32_t cell_key(float xr, float yr, float zr) {
  float x01 = (xr + 1.0f) * 0.5f;
  float y01 = (yr + 1.0f) * 0.5f;
  float z01 = (zr + 1.0f) * 0.5f;
  int cx = (int)(x01 * (float)SORT_RES);
  int cy = (int)(y01 * (float)SORT_RES);
  int cz = (int)(z01 * (float)SORT_RES);
  cx = cx < 0 ? 0 : (cx > SORT_RES-1 ? SORT_RES-1 : cx);
  cy = cy < 0 ? 0 : (cy > SORT_RES-1 ? SORT_RES-1 : cy);
  cz = cz < 0 ? 0 : (cz > SORT_RES-1 ? SORT_RES-1 : cz);
  return (uint32_t)(cx | (cy << 5) | (cz << 10));
}

// ---------------- sort machinery ----------------
__global__ __launch_bounds__(256) void zero_bins_kernel(uint32_t* bins) {
  int i = blockIdx.x * 256 + threadIdx.x;
  if (i < NBINS) bins[i] = 0u;
}

__global__ __launch_bounds__(256) void hist_kernel(
    const float* __restrict__ positions, uint32_t* __restrict__ bins, int n) {
  int t = blockIdx.x * 256 + threadIdx.x;
  int p0 = t * 4;
  if (p0 >= n) return;
  const float4 A = *reinterpret_cast<const float4*>(positions + 3*p0);
  const float4 B = *reinterpret_cast<const float4*>(positions + 3*p0 + 4);
  const float4 C = *reinterpret_cast<const float4*>(positions + 3*p0 + 8);
  atomicAdd(&bins[cell_key(A.x, A.y, A.z)], 1u);
  atomicAdd(&bins[cell_key(A.w, B.x, B.y)], 1u);
  atomicAdd(&bins[cell_key(B.z, B.w, C.x)], 1u);
  atomicAdd(&bins[cell_key(C.y, C.z, C.w)], 1u);
}

__global__ __launch_bounds__(1024) void scan_kernel(
    const uint32_t* __restrict__ bins, uint32_t* __restrict__ cursor) {
  __shared__ uint32_t lds[1024];
  int t = threadIdx.x;
  uint32_t local[32];
  uint32_t s = 0;
  #pragma unroll
  for (int j = 0; j < 32; ++j) { local[j] = bins[t*32 + j]; s += local[j]; }
  lds[t] = s;
  __syncthreads();
  for (int off = 1; off < 1024; off <<= 1) {
    uint32_t v = (t >= off) ? lds[t - off] : 0u;
    __syncthreads();
    lds[t] += v;
    __syncthreads();
  }
  uint32_t run = lds[t] - s;
  #pragma unroll
  for (int j = 0; j < 32; ++j) { cursor[t*32 + j] = run; run += local[j]; }
}

// 1 pt/thread (R9-proven best: 4096 blocks -> TLP hides atomic+store latency)
__global__ __launch_bounds__(256) void scatter_kernel(
    const float* __restrict__ positions, uint32_t* __restrict__ cursor,
    evu4* __restrict__ spi, int n) {
  int p = blockIdx.x * 256 + threadIdx.x;
  if (p >= n) return;
  float x = positions[3*p], y = positions[3*p+1], z = positions[3*p+2];
  uint32_t k = cell_key(x, y, z);
  uint32_t dst = atomicAdd(&cursor[k], 1u);
  evu4 v;
  v.x = __float_as_uint(x);
  v.y = __float_as_uint(y);
  v.z = __float_as_uint(z);
  v.w = (uint32_t)p;
  spi[dst] = v;
}

// ---------- per-point hashed-level feature ----------
__device__ __forceinline__ void hash_feat(
    float x01, float y01, float z01, float scale, uint32_t mask,
    const float* __restrict__ tbl, float& f0, float& f1)
{
  float px = x01 * scale + 0.5f;
  float py = y01 * scale + 0.5f;
  float pz = z01 * scale + 0.5f;
  float fx = floorf(px), fy = floorf(py), fz = floorf(pz);
  float tx = px - fx, ty = py - fy, tz = pz - fz;
  uint32_t gx = (uint32_t)fx, gy = (uint32_t)fy, gz = (uint32_t)fz;

  float wxa = 1.0f - tx, wxb = tx;
  float wy_[2] = {1.0f - ty, ty};
  float wz_[2] = {1.0f - tz, tz};

  f0 = 0.0f; f1 = 0.0f;
  if ((gx & 1u) == 0u) {
    #pragma unroll
    for (int cyz = 0; cyz < 4; ++cyz) {
      uint32_t cy = gy + (cyz & 1u);
      uint32_t cz = gz + (cyz >> 1);
      uint32_t hy = (cy * 2654435761u) ^ (cz * 805459861u);
      uint32_t ha = (gx ^ hy) & mask;
      float wyz = wy_[cyz & 1u] * wz_[cyz >> 1];
      float wa = wxa * wyz, wb = wxb * wyz;
      const float4 t4 = *reinterpret_cast<const float4*>(tbl + 2u * (ha & ~1u));
      float2 ta, tb;
      if (ha & 1u) { ta.x = t4.z; ta.y = t4.w; tb.x = t4.x; tb.y = t4.y; }
      else         { ta.x = t4.x; ta.y = t4.y; tb.x = t4.z; tb.y = t4.w; }
      f0 += wa * ta.x; f1 += wa * ta.y;
      f0 += wb * tb.x; f1 += wb * tb.y;
    }
  } else {
    #pragma unroll
    for (int cyz = 0; cyz < 4; ++cyz) {
      uint32_t cy = gy + (cyz & 1u);
      uint32_t cz = gz + (cyz >> 1);
      uint32_t hy = (cy * 2654435761u) ^ (cz * 805459861u);
      uint32_t ha = (gx ^ hy) & mask;
      uint32_t hb = ((gx + 1u) ^ hy) & mask;
      float wyz = wy_[cyz & 1u] * wz_[cyz >> 1];
      float wa = wxa * wyz, wb = wxb * wyz;
      const float2 ta = *reinterpret_cast<const float2*>(tbl + 2u * ha);
      const float2 tb = *reinterpret_cast<const float2*>(tbl + 2u * hb);
      f0 += wa * ta.x; f1 += wa * ta.y;
      f0 += wb * tb.x; f1 += wb * tb.y;
    }
  }
}

// ---------- merged hashed levels 6..11 ----------
__global__ __launch_bounds__(256) void hash_multi_kernel(
    const evu4* __restrict__ spi,
    const float* __restrict__ table,
    evh2* __restrict__ tmpH,            // slots 0..5 <- levels 6..11
    ParamsH ph, uint32_t mask, int n)
{
  int bid = xcd_swz(blockIdx.x, gridDim.x);
  int t = bid * 256 + threadIdx.x;
  int p0 = t * 2;
  if (p0 >= n) return;

  evu4 a = __builtin_nontemporal_load(spi + p0);
  evu4 b = __builtin_nontemporal_load(spi + p0 + 1);
  float x0 = (__uint_as_float(a.x) + 1.0f) * 0.5f;
  float y0 = (__uint_as_float(a.y) + 1.0f) * 0.5f;
  float z0 = (__uint_as_float(a.z) + 1.0f) * 0.5f;
  float x1 = (__uint_as_float(b.x) + 1.0f) * 0.5f;
  float y1 = (__uint_as_float(b.y) + 1.0f) * 0.5f;
  float z1 = (__uint_as_float(b.z) + 1.0f) * 0.5f;

  #pragma unroll
  for (int l = 0; l < NMERGE; ++l) {
    const float s = ph.scale[l];
    const float* __restrict__ tbl = table + 2u * ph.offset[l];
    float f00, f01, f10, f11;
    hash_feat(x0, y0, z0, s, mask, tbl, f00, f01);
    hash_feat(x1, y1, z1, s, mask, tbl, f10, f11);
    evh4 v;
    v.x = (_Float16)f00; v.y = (_Float16)f01;
    v.z = (_Float16)f10; v.w = (_Float16)f11;
    __builtin_nontemporal_store(v,
        reinterpret_cast<evh4*>(tmpH + (size_t)l * n + p0));
  }
}

// ---------- merged hashed levels 12..15 ----------
__global__ __launch_bounds__(256) void hash_multi2_kernel(
    const evu4* __restrict__ spi,
    const float* __restrict__ table,
    evh2* __restrict__ tmpH,            // slots 6..9 <- levels 12..15
    ParamsH2 ph, uint32_t mask, int n)
{
  int bid = xcd_swz(blockIdx.x, gridDim.x);
  int t = bid * 256 + threadIdx.x;
  int p0 = t * 2;
  if (p0 >= n) return;

  evu4 a = __builtin_nontemporal_load(spi + p0);
  evu4 b = __builtin_nontemporal_load(spi + p0 + 1);
  float x0 = (__uint_as_float(a.x) + 1.0f) * 0.5f;
  float y0 = (__uint_as_float(a.y) + 1.0f) * 0.5f;
  float z0 = (__uint_as_float(a.z) + 1.0f) * 0.5f;
  float x1 = (__uint_as_float(b.x) + 1.0f) * 0.5f;
  float y1 = (__uint_as_float(b.y) + 1.0f) * 0.5f;
  float z1 = (__uint_as_float(b.z) + 1.0f) * 0.5f;

  #pragma unroll
  for (int l = 0; l < NMERGE2; ++l) {
    const float s = ph.scale[l];
    const float* __restrict__ tbl = table + 2u * ph.offset[l];
    float f00, f01, f10, f11;
    hash_feat(x0, y0, z0, s, mask, tbl, f00, f01);
    hash_feat(x1, y1, z1, s, mask, tbl, f10, f11);
    evh4 v;
    v.x = (_Float16)f00; v.y = (_Float16)f01;
    v.z = (_Float16)f10; v.w = (_Float16)f11;
    __builtin_nontemporal_store(v,
        reinterpret_cast<evh4*>(tmpH + (size_t)(NMERGE + l) * n + p0));
  }
}

// ---------- fused: dense gathers + hash tmps + un-sort pack ----------
#define PBS 128
__global__ __launch_bounds__(PBS) void dense_pack2_kernel(
    const evu4* __restrict__ spi,
    const float* __restrict__ table,
    const evh2* __restrict__ tmpH,      // [NHASH][n] half2, sorted space
    float* __restrict__ out,
    ParamsD prm, int n)
{
  __shared__ float lds[PBS * 33];
  __shared__ uint32_t lds_oi[PBS];
  int t = threadIdx.x;
  int base = xcd_swz(blockIdx.x, gridDim.x) * PBS;
  int p = base + t;

  if (p < n) {
    evu4 a = __builtin_nontemporal_load(spi + p);
    float x = (__uint_as_float(a.x) + 1.0f) * 0.5f;
    float y = (__uint_as_float(a.y) + 1.0f) * 0.5f;
    float z = (__uint_as_float(a.z) + 1.0f) * 0.5f;
    lds_oi[t] = a.w;

    #pragma unroll
    for (int l = 0; l < NDENSE; ++l) {
      const float s = prm.scale[l];
      const uint32_t res = prm.res[l];
      const uint32_t ms = prm.msize[l];
      const float* __restrict__ tbl = table + 2u * prm.offset[l];
      const uint32_t res2 = res * res;

      float px = x * s + 0.5f;
      float py = y * s + 0.5f;
      float pz = z * s + 0.5f;
      float fx = floorf(px), fy = floorf(py), fz = floorf(pz);
      float tx = px - fx, ty = py - fy, tz = pz - fz;
      uint32_t gx = (uint32_t)fx, gy = (uint32_t)fy, gz = (uint32_t)fz;

      float wxa = 1.0f - tx, wxb = tx;
      float wy_[2] = {1.0f - ty, ty};
      float wz_[2] = {1.0f - tz, tz};

      float f0 = 0.0f, f1 = 0.0f;
      #pragma unroll
      for (int cyz = 0; cyz < 4; ++cyz) {
        uint32_t cy = gy + (cyz & 1u);
        uint32_t cz = gz + ((cyz >> 1) & 1u);
        uint32_t h = gx + cy * res + cz * res2;   // raw in [0, 2*ms)
        if (h >= ms) h -= ms;
        float wyz = wy_[cyz & 1u] * wz_[(cyz >> 1) & 1u];
        float2 ta, tb;
        if (h + 1u < ms) {
          const float4 t4 = *reinterpret_cast<const float4*>(tbl + 2u * h);
          ta.x = t4.x; ta.y = t4.y; tb.x = t4.z; tb.y = t4.w;
        } else {                                  // h == ms-1: b wraps to 0
          ta = *reinterpret_cast<const float2*>(tbl + 2u * h);
          tb = *reinterpret_cast<const float2*>(tbl);
        }
        float wa = wxa * wyz, wb = wxb * wyz;
        f0 += wa * ta.x; f1 += wa * ta.y;
        f0 += wb * tb.x; f1 += wb * tb.y;
      }
      lds[t*33 + 2*l]     = f0;
      lds[t*33 + 2*l + 1] = f1;
    }

    #pragma unroll
    for (int j = 0; j < NHASH; ++j) {
      evh2 v = __builtin_nontemporal_load(tmpH + (size_t)j * n + p);
      lds[t*33 + 12 + 2*j]     = (float)v.x;
      lds[t*33 + 12 + 2*j + 1] = (float)v.y;
    }
  }
  __syncthreads();

  if (base + PBS <= n) {
    // per instruction, each WAVE writes 8 complete 128-B lines -> nt is safe
    // (no partial-line flush, unlike R4's strided layout) and keeps 128 MB of
    // write-once output from evicting the dense tables out of L2.
    int qr = t >> 3, r = t & 7;
    #pragma unroll
    for (int k = 0; k < 8; ++k) {
      int q = k * (PBS/8) + qr;
      uint32_t oi = lds_oi[q];
      evf4 v;
      v.x = lds[q*33 + r*4];     v.y = lds[q*33 + r*4 + 1];
      v.z = lds[q*33 + r*4 + 2]; v.w = lds[q*33 + r*4 + 3];
      __builtin_nontemporal_store(v,
          reinterpret_cast<evf4*>(out + (size_t)oi * 32u) + r);
    }
  } else if (p < n) {
    uint32_t oi = lds_oi[t];
    float4* o = reinterpret_cast<float4*>(out + (size_t)oi * 32u);
    #pragma unroll
    for (int k = 0; k < 8; ++k)
      o[k] = make_float4(lds[t*33 + 4*k], lds[t*33 + 4*k + 1],
                         lds[t*33 + 4*k + 2], lds[t*33 + 4*k + 3]);
  }
}

// ---------- last-resort fallback: single fused kernel ----------
__global__ __launch_bounds__(256) void hash_enc_kernel(
    const float* __restrict__ positions,
    const float* __restrict__ table,
    float* __restrict__ out,
    Params prm, int n)
{
  int p = blockIdx.x * 256 + threadIdx.x;
  if (p >= n) return;

  float x = (positions[3*p+0] + 1.0f) * 0.5f;
  float y = (positions[3*p+1] + 1.0f) * 0.5f;
  float z = (positions[3*p+2] + 1.0f) * 0.5f;

  float acc[32];

  #pragma unroll
  for (int l = 0; l < NLV; ++l) {
    const float s = prm.scale[l];
    const uint32_t res = prm.res[l];
    const uint32_t ms = prm.msize[l];
    const uint32_t off = prm.offset[l];
    float px = x * s + 0.5f;
    float py = y * s + 0.5f;
    float pz = z * s + 0.5f;
    float fx = floorf(px), fy = floorf(py), fz = floorf(pz);
    float tx = px - fx, ty = py - fy, tz = pz - fz;
    uint32_t gx = (uint32_t)fx, gy = (uint32_t)fy, gz = (uint32_t)fz;
    float wx[2] = {1.0f - tx, tx};
    float wy[2] = {1.0f - ty, ty};
    float wz[2] = {1.0f - tz, tz};
    float f0 = 0.0f, f1 = 0.0f;
    #pragma unroll
    for (int c = 0; c < 8; ++c) {
      uint32_t cx = gx + (c & 1u);
      uint32_t cy = gy + ((c >> 1) & 1u);
      uint32_t cz = gz + ((c >> 2) & 1u);
      uint32_t h;
      if (l < NDENSE) {
        h = cx + cy * res + cz * res * res;
        if (h >= ms) h -= ms;
      } else {
        h = cx ^ (cy * 2654435761u) ^ (cz * 805459861u);
        h &= (ms - 1u);
      }
      float w = (wx[c & 1u] * wy[(c >> 1) & 1u]) * wz[(c >> 2) & 1u];
      const float2 t = *reinterpret_cast<const float2*>(table + 2u * (h + off));
      f0 += w * t.x;
      f1 += w * t.y;
    }
    acc[2*l]   = f0;
    acc[2*l+1] = f1;
  }

  float4* o = reinterpret_cast<float4*>(out + (size_t)p * 32u);
  #pragma unroll
  for (int k = 0; k < 8; ++k)
    o[k] = make_float4(acc[4*k+0], acc[4*k+1], acc[4*k+2], acc[4*k+3]);
}

extern "C" void kernel_launch(void* const* d_in, const int* in_sizes, int n_in,
                              void* d_out, int out_size, void* d_ws, size_t ws_size,
                              hipStream_t stream) {
  const float* positions = (const float*)d_in[0];
  const float* table     = (const float*)d_in[1];
  float* out             = (float*)d_out;
  int n = in_sizes[0] / 3;

  // Level metadata, exactly mirroring the reference (f64 exp/log; f32 cast
  // for the encode-path scale; level 5 is dense with res=65 due to the
  // B_SCALE^5 = 4.0000007 float quirk).
  Params prm;
  const double lnb = log(1.3195079565048218);
  uint32_t off = 0;
  for (int l = 0; l < NLV; ++l) {
    double sd = 16.0 * exp((double)l * lnb) - 1.0;
    uint32_t res_meta = (uint32_t)ceil(sd) + 1u;
    uint64_t p3 = (uint64_t)res_meta * res_meta * res_meta;
    uint64_t ps = (p3 % 8ull) ? ((p3 + 7ull) / 8ull) * 8ull : p3;
    if (ps > (1ull << 19)) ps = 1ull << 19;
    float sf = (float)sd;
    uint32_t res_enc = (uint32_t)(ceilf(sf) + 1.0f);
    prm.scale[l]  = sf;
    prm.res[l]    = res_enc;
    prm.msize[l]  = (uint32_t)ps;
    prm.offset[l] = off;
    off += (uint32_t)ps;
  }
  ParamsD pd;
  for (int l = 0; l < NDENSE; ++l) {
    pd.scale[l] = prm.scale[l]; pd.res[l] = prm.res[l];
    pd.msize[l] = prm.msize[l]; pd.offset[l] = prm.offset[l];
  }
  ParamsH ph;
  for (int l = 0; l < NMERGE; ++l) {
    ph.scale[l]  = prm.scale[NDENSE + l];
    ph.offset[l] = prm.offset[NDENSE + l];
  }
  ParamsH2 ph2;
  for (int l = 0; l < NMERGE2; ++l) {
    ph2.scale[l]  = prm.scale[NDENSE + NMERGE + l];
    ph2.offset[l] = prm.offset[NDENSE + NMERGE + l];
  }

  dim3 block(256);
  dim3 gfull((n + 255) / 256);
  dim3 ghash((n/2 + 255) / 256);
  dim3 gquad((n/4 + 255) / 256);
  dim3 gpack((n + PBS - 1) / PBS);

  // sorted-path ws layout: [tmpH 10*n*4][spi n*16][bins][cursor]
  size_t tmp_b  = (size_t)NHASH * n * sizeof(evh2);
  size_t sp_off = tmp_b;
  size_t bn_off = sp_off + (size_t)n * sizeof(evu4);
  size_t cu_off = bn_off + (size_t)NBINS * sizeof(uint32_t);
  size_t total  = cu_off + (size_t)NBINS * sizeof(uint32_t);

  char* wsb = (char*)d_ws;

  if (ws_size >= total && (n % 4) == 0) {
    // ---- sorted path ----
    evh2*     tmpH   = (evh2*)wsb;
    evu4*     spi    = (evu4*)(wsb + sp_off);
    uint32_t* bins   = (uint32_t*)(wsb + bn_off);
    uint32_t* cursor = (uint32_t*)(wsb + cu_off);

    hipLaunchKernelGGL(zero_bins_kernel, dim3((NBINS + 255) / 256), block, 0, stream, bins);
    hipLaunchKernelGGL(hist_kernel, gquad, block, 0, stream, positions, bins, n);
    hipLaunchKernelGGL(scan_kernel, dim3(1), dim3(1024), 0, stream, bins, cursor);
    hipLaunchKernelGGL(scatter_kernel, gfull, block, 0, stream,
                       positions, cursor, spi, n);

    hipLaunchKernelGGL(hash_multi_kernel, ghash, block, 0, stream,
                       spi, table, tmpH, ph, prm.msize[NDENSE] - 1u, n);
    hipLaunchKernelGGL(hash_multi2_kernel, ghash, block, 0, stream,
                       spi, table, tmpH, ph2, prm.msize[NDENSE] - 1u, n);
    hipLaunchKernelGGL(dense_pack2_kernel, gpack, dim3(PBS), 0, stream,
                       spi, table, tmpH, out, pd, n);
  } else {
    // fallback: correct single-kernel path
    hipLaunchKernelGGL(hash_enc_kernel, gfull, block, 0, stream,
                       positions, table, out, prm, n);
  }
}

// Round 15
// 430.325 us; speedup vs baseline: 1.1642x; 1.1642x over previous
//
#include <hip/hip_runtime.h>
#include <math.h>
#include <stdint.h>

#define NLV 16
#define NDENSE 6
#define NHASH 10
#define NMERGE 6          // hashed levels 6..11 merged (coarse: window-local)
#define SORT_RES 32
#define NBINS (SORT_RES * SORT_RES * SORT_RES)   // 32768

typedef float evf2 __attribute__((ext_vector_type(2)));
typedef float evf4 __attribute__((ext_vector_type(4)));
typedef unsigned int evu4 __attribute__((ext_vector_type(4)));
typedef _Float16 evh2 __attribute__((ext_vector_type(2)));
typedef _Float16 evh4 __attribute__((ext_vector_type(4)));

struct Params {
  float scale[NLV];
  uint32_t res[NLV];
  uint32_t msize[NLV];
  uint32_t offset[NLV];
};

struct ParamsD {
  float scale[NDENSE];
  uint32_t res[NDENSE];
  uint32_t msize[NDENSE];
  uint32_t offset[NDENSE];
};

struct ParamsH {
  float scale[NMERGE];
  uint32_t offset[NMERGE];
};

// bijective XCD swizzle (m204)
__device__ __forceinline__ int xcd_swz(int bid, int nwg) {
  int q = nwg >> 3, r = nwg & 7;
  int x = bid & 7, i = bid >> 3;
  return (x < r ? x * (q + 1) : r * (q + 1) + (x - r) * q) + i;
}

__device__ __forceinline__ uint32_t cell_key(float xr, float yr, float zr) {
  float x01 = (xr + 1.0f) * 0.5f;
  float y01 = (yr + 1.0f) * 0.5f;
  float z01 = (zr + 1.0f) * 0.5f;
  int cx = (int)(x01 * (float)SORT_RES);
  int cy = (int)(y01 * (float)SORT_RES);
  int cz = (int)(z01 * (float)SORT_RES);
  cx = cx < 0 ? 0 : (cx > SORT_RES-1 ? SORT_RES-1 : cx);
  cy = cy < 0 ? 0 : (cy > SORT_RES-1 ? SORT_RES-1 : cy);
  cz = cz < 0 ? 0 : (cz > SORT_RES-1 ? SORT_RES-1 : cz);
  return (uint32_t)(cx | (cy << 5) | (cz << 10));
}

// ---------------- sort machinery ----------------
__global__ __launch_bounds__(256) void zero_bins_kernel(uint32_t* bins) {
  int i = blockIdx.x * 256 + threadIdx.x;
  if (i < NBINS) bins[i] = 0u;
}

__global__ __launch_bounds__(256) void hist_kernel(
    const float* __restrict__ positions, uint32_t* __restrict__ bins, int n) {
  int t = blockIdx.x * 256 + threadIdx.x;
  int p0 = t * 4;
  if (p0 >= n) return;
  const float4 A = *reinterpret_cast<const float4*>(positions + 3*p0);
  const float4 B = *reinterpret_cast<const float4*>(positions + 3*p0 + 4);
  const float4 C = *reinterpret_cast<const float4*>(positions + 3*p0 + 8);
  atomicAdd(&bins[cell_key(A.x, A.y, A.z)], 1u);
  atomicAdd(&bins[cell_key(A.w, B.x, B.y)], 1u);
  atomicAdd(&bins[cell_key(B.z, B.w, C.x)], 1u);
  atomicAdd(&bins[cell_key(C.y, C.z, C.w)], 1u);
}

__global__ __launch_bounds__(1024) void scan_kernel(
    const uint32_t* __restrict__ bins, uint32_t* __restrict__ cursor) {
  __shared__ uint32_t lds[1024];
  int t = threadIdx.x;
  uint32_t local[32];
  uint32_t s = 0;
  #pragma unroll
  for (int j = 0; j < 32; ++j) { local[j] = bins[t*32 + j]; s += local[j]; }
  lds[t] = s;
  __syncthreads();
  for (int off = 1; off < 1024; off <<= 1) {
    uint32_t v = (t >= off) ? lds[t - off] : 0u;
    __syncthreads();
    lds[t] += v;
    __syncthreads();
  }
  uint32_t run = lds[t] - s;
  #pragma unroll
  for (int j = 0; j < 32; ++j) { cursor[t*32 + j] = run; run += local[j]; }
}

// 1 pt/thread (R9-proven: 4096 blocks -> TLP hides atomic+store latency)
__global__ __launch_bounds__(256) void scatter_kernel(
    const float* __restrict__ positions, uint32_t* __restrict__ cursor,
    evu4* __restrict__ spi, int n) {
  int p = blockIdx.x * 256 + threadIdx.x;
  if (p >= n) return;
  float x = positions[3*p], y = positions[3*p+1], z = positions[3*p+2];
  uint32_t k = cell_key(x, y, z);
  uint32_t dst = atomicAdd(&cursor[k], 1u);
  evu4 v;
  v.x = __float_as_uint(x);
  v.y = __float_as_uint(y);
  v.z = __float_as_uint(z);
  v.w = (uint32_t)p;
  spi[dst] = v;
}

// ---------- per-point hashed-level feature ----------
__device__ __forceinline__ void hash_feat(
    float x01, float y01, float z01, float scale, uint32_t mask,
    const float* __restrict__ tbl, float& f0, float& f1)
{
  float px = x01 * scale + 0.5f;
  float py = y01 * scale + 0.5f;
  float pz = z01 * scale + 0.5f;
  float fx = floorf(px), fy = floorf(py), fz = floorf(pz);
  float tx = px - fx, ty = py - fy, tz = pz - fz;
  uint32_t gx = (uint32_t)fx, gy = (uint32_t)fy, gz = (uint32_t)fz;

  float wxa = 1.0f - tx, wxb = tx;
  float wy_[2] = {1.0f - ty, ty};
  float wz_[2] = {1.0f - tz, tz};

  f0 = 0.0f; f1 = 0.0f;
  if ((gx & 1u) == 0u) {
    #pragma unroll
    for (int cyz = 0; cyz < 4; ++cyz) {
      uint32_t cy = gy + (cyz & 1u);
      uint32_t cz = gz + (cyz >> 1);
      uint32_t hy = (cy * 2654435761u) ^ (cz * 805459861u);
      uint32_t ha = (gx ^ hy) & mask;
      float wyz = wy_[cyz & 1u] * wz_[cyz >> 1];
      float wa = wxa * wyz, wb = wxb * wyz;
      const float4 t4 = *reinterpret_cast<const float4*>(tbl + 2u * (ha & ~1u));
      float2 ta, tb;
      if (ha & 1u) { ta.x = t4.z; ta.y = t4.w; tb.x = t4.x; tb.y = t4.y; }
      else         { ta.x = t4.x; ta.y = t4.y; tb.x = t4.z; tb.y = t4.w; }
      f0 += wa * ta.x; f1 += wa * ta.y;
      f0 += wb * tb.x; f1 += wb * tb.y;
    }
  } else {
    #pragma unroll
    for (int cyz = 0; cyz < 4; ++cyz) {
      uint32_t cy = gy + (cyz & 1u);
      uint32_t cz = gz + (cyz >> 1);
      uint32_t hy = (cy * 2654435761u) ^ (cz * 805459861u);
      uint32_t ha = (gx ^ hy) & mask;
      uint32_t hb = ((gx + 1u) ^ hy) & mask;
      float wyz = wy_[cyz & 1u] * wz_[cyz >> 1];
      float wa = wxa * wyz, wb = wxb * wyz;
      const float2 ta = *reinterpret_cast<const float2*>(tbl + 2u * ha);
      const float2 tb = *reinterpret_cast<const float2*>(tbl + 2u * hb);
      f0 += wa * ta.x; f1 += wa * ta.y;
      f0 += wb * tb.x; f1 += wb * tb.y;
    }
  }
}

// ---------- merged hashed levels 6..11 (coarse: sorted waves hit few windows,
// combined hot footprint << L2; R14 lesson: do NOT merge fine levels 12..15,
// whose hot footprint is 4 full 4 MB tables -> L2 thrash, FETCH 687 MB) ----------
__global__ __launch_bounds__(256) void hash_multi_kernel(
    const evu4* __restrict__ spi,
    const float* __restrict__ table,
    evh2* __restrict__ tmpH,            // slots 0..5 <- levels 6..11
    ParamsH ph, uint32_t mask, int n)
{
  int bid = xcd_swz(blockIdx.x, gridDim.x);
  int t = bid * 256 + threadIdx.x;
  int p0 = t * 2;
  if (p0 >= n) return;

  evu4 a = __builtin_nontemporal_load(spi + p0);
  evu4 b = __builtin_nontemporal_load(spi + p0 + 1);
  float x0 = (__uint_as_float(a.x) + 1.0f) * 0.5f;
  float y0 = (__uint_as_float(a.y) + 1.0f) * 0.5f;
  float z0 = (__uint_as_float(a.z) + 1.0f) * 0.5f;
  float x1 = (__uint_as_float(b.x) + 1.0f) * 0.5f;
  float y1 = (__uint_as_float(b.y) + 1.0f) * 0.5f;
  float z1 = (__uint_as_float(b.z) + 1.0f) * 0.5f;

  #pragma unroll
  for (int l = 0; l < NMERGE; ++l) {
    const float s = ph.scale[l];
    const float* __restrict__ tbl = table + 2u * ph.offset[l];
    float f00, f01, f10, f11;
    hash_feat(x0, y0, z0, s, mask, tbl, f00, f01);
    hash_feat(x1, y1, z1, s, mask, tbl, f10, f11);
    evh4 v;
    v.x = (_Float16)f00; v.y = (_Float16)f01;
    v.z = (_Float16)f10; v.w = (_Float16)f11;
    __builtin_nontemporal_store(v,
        reinterpret_cast<evh4*>(tmpH + (size_t)l * n + p0));
  }
}

// ---------- single fine hashed level (12..15): one 4 MB table hot per pass ----------
__global__ __launch_bounds__(256) void hash_level_kernel(
    const evu4* __restrict__ spi,
    const float* __restrict__ tbl,
    evh2* __restrict__ tmpH,
    float scale, uint32_t mask, int n)
{
  int bid = xcd_swz(blockIdx.x, gridDim.x);
  int t = bid * 256 + threadIdx.x;
  int p0 = t * 2;
  if (p0 >= n) return;

  evu4 a = __builtin_nontemporal_load(spi + p0);
  evu4 b = __builtin_nontemporal_load(spi + p0 + 1);
  float f00, f01, f10, f11;
  hash_feat((__uint_as_float(a.x) + 1.0f) * 0.5f,
            (__uint_as_float(a.y) + 1.0f) * 0.5f,
            (__uint_as_float(a.z) + 1.0f) * 0.5f, scale, mask, tbl, f00, f01);
  hash_feat((__uint_as_float(b.x) + 1.0f) * 0.5f,
            (__uint_as_float(b.y) + 1.0f) * 0.5f,
            (__uint_as_float(b.z) + 1.0f) * 0.5f, scale, mask, tbl, f10, f11);
  evh4 v;
  v.x = (_Float16)f00; v.y = (_Float16)f01;
  v.z = (_Float16)f10; v.w = (_Float16)f11;
  __builtin_nontemporal_store(v, reinterpret_cast<evh4*>(tmpH + p0));
}

// ---------- fused: dense gathers + hash tmps + un-sort pack ----------
#define PBS 128
__global__ __launch_bounds__(PBS) void dense_pack2_kernel(
    const evu4* __restrict__ spi,
    const float* __restrict__ table,
    const evh2* __restrict__ tmpH,      // [NHASH][n] half2, sorted space
    float* __restrict__ out,
    ParamsD prm, int n)
{
  __shared__ float lds[PBS * 33];
  __shared__ uint32_t lds_oi[PBS];
  int t = threadIdx.x;
  int base = xcd_swz(blockIdx.x, gridDim.x) * PBS;
  int p = base + t;

  if (p < n) {
    evu4 a = __builtin_nontemporal_load(spi + p);
    float x = (__uint_as_float(a.x) + 1.0f) * 0.5f;
    float y = (__uint_as_float(a.y) + 1.0f) * 0.5f;
    float z = (__uint_as_float(a.z) + 1.0f) * 0.5f;
    lds_oi[t] = a.w;

    #pragma unroll
    for (int l = 0; l < NDENSE; ++l) {
      const float s = prm.scale[l];
      const uint32_t res = prm.res[l];
      const uint32_t ms = prm.msize[l];
      const float* __restrict__ tbl = table + 2u * prm.offset[l];
      const uint32_t res2 = res * res;

      float px = x * s + 0.5f;
      float py = y * s + 0.5f;
      float pz = z * s + 0.5f;
      float fx = floorf(px), fy = floorf(py), fz = floorf(pz);
      float tx = px - fx, ty = py - fy, tz = pz - fz;
      uint32_t gx = (uint32_t)fx, gy = (uint32_t)fy, gz = (uint32_t)fz;

      float wxa = 1.0f - tx, wxb = tx;
      float wy_[2] = {1.0f - ty, ty};
      float wz_[2] = {1.0f - tz, tz};

      float f0 = 0.0f, f1 = 0.0f;
      #pragma unroll
      for (int cyz = 0; cyz < 4; ++cyz) {
        uint32_t cy = gy + (cyz & 1u);
        uint32_t cz = gz + ((cyz >> 1) & 1u);
        uint32_t h = gx + cy * res + cz * res2;   // raw in [0, 2*ms)
        if (h >= ms) h -= ms;
        float wyz = wy_[cyz & 1u] * wz_[(cyz >> 1) & 1u];
        float2 ta, tb;
        if (h + 1u < ms) {
          const float4 t4 = *reinterpret_cast<const float4*>(tbl + 2u * h);
          ta.x = t4.x; ta.y = t4.y; tb.x = t4.z; tb.y = t4.w;
        } else {                                  // h == ms-1: b wraps to 0
          ta = *reinterpret_cast<const float2*>(tbl + 2u * h);
          tb = *reinterpret_cast<const float2*>(tbl);
        }
        float wa = wxa * wyz, wb = wxb * wyz;
        f0 += wa * ta.x; f1 += wa * ta.y;
        f0 += wb * tb.x; f1 += wb * tb.y;
      }
      lds[t*33 + 2*l]     = f0;
      lds[t*33 + 2*l + 1] = f1;
    }

    #pragma unroll
    for (int j = 0; j < NHASH; ++j) {
      evh2 v = __builtin_nontemporal_load(tmpH + (size_t)j * n + p);
      lds[t*33 + 12 + 2*j]     = (float)v.x;
      lds[t*33 + 12 + 2*j + 1] = (float)v.y;
    }
  }
  __syncthreads();

  if (base + PBS <= n) {
    // per instruction each WAVE writes 8 complete 128-B lines -> nt is safe
    // (no partial-line flush) and keeps the write-once output out of L2.
    int qr = t >> 3, r = t & 7;
    #pragma unroll
    for (int k = 0; k < 8; ++k) {
      int q = k * (PBS/8) + qr;
      uint32_t oi = lds_oi[q];
      evf4 v;
      v.x = lds[q*33 + r*4];     v.y = lds[q*33 + r*4 + 1];
      v.z = lds[q*33 + r*4 + 2]; v.w = lds[q*33 + r*4 + 3];
      __builtin_nontemporal_store(v,
          reinterpret_cast<evf4*>(out + (size_t)oi * 32u) + r);
    }
  } else if (p < n) {
    uint32_t oi = lds_oi[t];
    float4* o = reinterpret_cast<float4*>(out + (size_t)oi * 32u);
    #pragma unroll
    for (int k = 0; k < 8; ++k)
      o[k] = make_float4(lds[t*33 + 4*k], lds[t*33 + 4*k + 1],
                         lds[t*33 + 4*k + 2], lds[t*33 + 4*k + 3]);
  }
}

// ---------- last-resort fallback: single fused kernel ----------
__global__ __launch_bounds__(256) void hash_enc_kernel(
    const float* __restrict__ positions,
    const float* __restrict__ table,
    float* __restrict__ out,
    Params prm, int n)
{
  int p = blockIdx.x * 256 + threadIdx.x;
  if (p >= n) return;

  float x = (positions[3*p+0] + 1.0f) * 0.5f;
  float y = (positions[3*p+1] + 1.0f) * 0.5f;
  float z = (positions[3*p+2] + 1.0f) * 0.5f;

  float acc[32];

  #pragma unroll
  for (int l = 0; l < NLV; ++l) {
    const float s = prm.scale[l];
    const uint32_t res = prm.res[l];
    const uint32_t ms = prm.msize[l];
    const uint32_t off = prm.offset[l];
    float px = x * s + 0.5f;
    float py = y * s + 0.5f;
    float pz = z * s + 0.5f;
    float fx = floorf(px), fy = floorf(py), fz = floorf(pz);
    float tx = px - fx, ty = py - fy, tz = pz - fz;
    uint32_t gx = (uint32_t)fx, gy = (uint32_t)fy, gz = (uint32_t)fz;
    float wx[2] = {1.0f - tx, tx};
    float wy[2] = {1.0f - ty, ty};
    float wz[2] = {1.0f - tz, tz};
    float f0 = 0.0f, f1 = 0.0f;
    #pragma unroll
    for (int c = 0; c < 8; ++c) {
      uint32_t cx = gx + (c & 1u);
      uint32_t cy = gy + ((c >> 1) & 1u);
      uint32_t cz = gz + ((c >> 2) & 1u);
      uint32_t h;
      if (l < NDENSE) {
        h = cx + cy * res + cz * res * res;
        if (h >= ms) h -= ms;
      } else {
        h = cx ^ (cy * 2654435761u) ^ (cz * 805459861u);
        h &= (ms - 1u);
      }
      float w = (wx[c & 1u] * wy[(c >> 1) & 1u]) * wz[(c >> 2) & 1u];
      const float2 t = *reinterpret_cast<const float2*>(table + 2u * (h + off));
      f0 += w * t.x;
      f1 += w * t.y;
    }
    acc[2*l]   = f0;
    acc[2*l+1] = f1;
  }

  float4* o = reinterpret_cast<float4*>(out + (size_t)p * 32u);
  #pragma unroll
  for (int k = 0; k < 8; ++k)
    o[k] = make_float4(acc[4*k+0], acc[4*k+1], acc[4*k+2], acc[4*k+3]);
}

extern "C" void kernel_launch(void* const* d_in, const int* in_sizes, int n_in,
                              void* d_out, int out_size, void* d_ws, size_t ws_size,
                              hipStream_t stream) {
  const float* positions = (const float*)d_in[0];
  const float* table     = (const float*)d_in[1];
  float* out             = (float*)d_out;
  int n = in_sizes[0] / 3;

  // Level metadata, exactly mirroring the reference (f64 exp/log; f32 cast
  // for the encode-path scale; level 5 is dense with res=65 due to the
  // B_SCALE^5 = 4.0000007 float quirk).
  Params prm;
  const double lnb = log(1.3195079565048218);
  uint32_t off = 0;
  for (int l = 0; l < NLV; ++l) {
    double sd = 16.0 * exp((double)l * lnb) - 1.0;
    uint32_t res_meta = (uint32_t)ceil(sd) + 1u;
    uint64_t p3 = (uint64_t)res_meta * res_meta * res_meta;
    uint64_t ps = (p3 % 8ull) ? ((p3 + 7ull) / 8ull) * 8ull : p3;
    if (ps > (1ull << 19)) ps = 1ull << 19;
    float sf = (float)sd;
    uint32_t res_enc = (uint32_t)(ceilf(sf) + 1.0f);
    prm.scale[l]  = sf;
    prm.res[l]    = res_enc;
    prm.msize[l]  = (uint32_t)ps;
    prm.offset[l] = off;
    off += (uint32_t)ps;
  }
  ParamsD pd;
  for (int l = 0; l < NDENSE; ++l) {
    pd.scale[l] = prm.scale[l]; pd.res[l] = prm.res[l];
    pd.msize[l] = prm.msize[l]; pd.offset[l] = prm.offset[l];
  }
  ParamsH ph;
  for (int l = 0; l < NMERGE; ++l) {
    ph.scale[l]  = prm.scale[NDENSE + l];
    ph.offset[l] = prm.offset[NDENSE + l];
  }

  dim3 block(256);
  dim3 gfull((n + 255) / 256);
  dim3 ghash((n/2 + 255) / 256);
  dim3 gquad((n/4 + 255) / 256);
  dim3 gpack((n + PBS - 1) / PBS);

  // sorted-path ws layout: [tmpH 10*n*4][spi n*16][bins][cursor]
  size_t tmp_b  = (size_t)NHASH * n * sizeof(evh2);
  size_t sp_off = tmp_b;
  size_t bn_off = sp_off + (size_t)n * sizeof(evu4);
  size_t cu_off = bn_off + (size_t)NBINS * sizeof(uint32_t);
  size_t total  = cu_off + (size_t)NBINS * sizeof(uint32_t);

  char* wsb = (char*)d_ws;

  if (ws_size >= total && (n % 4) == 0) {
    // ---- sorted path ----
    evh2*     tmpH   = (evh2*)wsb;
    evu4*     spi    = (evu4*)(wsb + sp_off);
    uint32_t* bins   = (uint32_t*)(wsb + bn_off);
    uint32_t* cursor = (uint32_t*)(wsb + cu_off);

    hipLaunchKernelGGL(zero_bins_kernel, dim3((NBINS + 255) / 256), block, 0, stream, bins);
    hipLaunchKernelGGL(hist_kernel, gquad, block, 0, stream, positions, bins, n);
    hipLaunchKernelGGL(scan_kernel, dim3(1), dim3(1024), 0, stream, bins, cursor);
    hipLaunchKernelGGL(scatter_kernel, gfull, block, 0, stream,
                       positions, cursor, spi, n);

    // coarse levels 6..11 merged; fine levels 12..15 one pass each (R14 lesson)
    hipLaunchKernelGGL(hash_multi_kernel, ghash, block, 0, stream,
                       spi, table, tmpH, ph, prm.msize[NDENSE] - 1u, n);
    for (int l = NDENSE + NMERGE; l < NLV; ++l) {
      hipLaunchKernelGGL(hash_level_kernel, ghash, block, 0, stream,
                         spi, table + 2u * prm.offset[l],
                         tmpH + (size_t)(l - NDENSE) * n,
                         prm.scale[l], prm.msize[l] - 1u, n);
    }
    hipLaunchKernelGGL(dense_pack2_kernel, gpack, dim3(PBS), 0, stream,
                       spi, table, tmpH, out, pd, n);
  } else {
    // fallback: correct single-kernel path
    hipLaunchKernelGGL(hash_enc_kernel, gfull, block, 0, stream,
                       positions, table, out, prm, n);
  }
}

// Round 16
// 392.340 us; speedup vs baseline: 1.2770x; 1.0968x over previous
//
#include <hip/hip_runtime.h>
#include <math.h>
#include <stdint.h>

#define NLV 16
#define NDENSE 6
#define NHASH 10
#define NMERGE 6          // hashed levels 6..11 merged (coarse: window-local)
#define SORT_RES 32
#define NBINS (SORT_RES * SORT_RES * SORT_RES)   // 32768

typedef float evf2 __attribute__((ext_vector_type(2)));
typedef float evf4 __attribute__((ext_vector_type(4)));
typedef unsigned int evu4 __attribute__((ext_vector_type(4)));
typedef _Float16 evh2 __attribute__((ext_vector_type(2)));
typedef _Float16 evh4 __attribute__((ext_vector_type(4)));

struct Params {
  float scale[NLV];
  uint32_t res[NLV];
  uint32_t msize[NLV];
  uint32_t offset[NLV];
};

struct ParamsD {
  float scale[NDENSE];
  uint32_t res[NDENSE];
  uint32_t msize[NDENSE];
  uint32_t offset[NDENSE];
};

struct ParamsH {
  float scale[NMERGE];
  uint32_t offset[NMERGE];
};

struct ParamsP {          // one pair of fine hashed levels
  float scale[2];
  uint32_t offset[2];
};

// bijective XCD swizzle (m204)
__device__ __forceinline__ int xcd_swz(int bid, int nwg) {
  int q = nwg >> 3, r = nwg & 7;
  int x = bid & 7, i = bid >> 3;
  return (x < r ? x * (q + 1) : r * (q + 1) + (x - r) * q) + i;
}

__device__ __forceinline__ uint32_t cell_key(float xr, float yr, float zr) {
  float x01 = (xr + 1.0f) * 0.5f;
  float y01 = (yr + 1.0f) * 0.5f;
  float z01 = (zr + 1.0f) * 0.5f;
  int cx = (int)(x01 * (float)SORT_RES);
  int cy = (int)(y01 * (float)SORT_RES);
  int cz = (int)(z01 * (float)SORT_RES);
  cx = cx < 0 ? 0 : (cx > SORT_RES-1 ? SORT_RES-1 : cx);
  cy = cy < 0 ? 0 : (cy > SORT_RES-1 ? SORT_RES-1 : cy);
  cz = cz < 0 ? 0 : (cz > SORT_RES-1 ? SORT_RES-1 : cz);
  return (uint32_t)(cx | (cy << 5) | (cz << 10));
}

// ---------------- f32 -> f16 table conversion (once; ~23 MB result) ----------------
__global__ __launch_bounds__(256) void cvt_kernel(
    const float* __restrict__ src, _Float16* __restrict__ dst, int nf) {
  int i4 = (blockIdx.x * 256 + threadIdx.x) * 4;
  if (i4 >= nf) return;
  const float4 v = *reinterpret_cast<const float4*>(src + i4);
  evh4 h;
  h.x = (_Float16)v.x; h.y = (_Float16)v.y;
  h.z = (_Float16)v.z; h.w = (_Float16)v.w;
  __builtin_nontemporal_store(h, reinterpret_cast<evh4*>(dst + i4));
}

// ---------------- sort machinery ----------------
__global__ __launch_bounds__(256) void zero_bins_kernel(uint32_t* bins) {
  int i = blockIdx.x * 256 + threadIdx.x;
  if (i < NBINS) bins[i] = 0u;
}

__global__ __launch_bounds__(256) void hist_kernel(
    const float* __restrict__ positions, uint32_t* __restrict__ bins, int n) {
  int t = blockIdx.x * 256 + threadIdx.x;
  int p0 = t * 4;
  if (p0 >= n) return;
  const float4 A = *reinterpret_cast<const float4*>(positions + 3*p0);
  const float4 B = *reinterpret_cast<const float4*>(positions + 3*p0 + 4);
  const float4 C = *reinterpret_cast<const float4*>(positions + 3*p0 + 8);
  atomicAdd(&bins[cell_key(A.x, A.y, A.z)], 1u);
  atomicAdd(&bins[cell_key(A.w, B.x, B.y)], 1u);
  atomicAdd(&bins[cell_key(B.z, B.w, C.x)], 1u);
  atomicAdd(&bins[cell_key(C.y, C.z, C.w)], 1u);
}

__global__ __launch_bounds__(1024) void scan_kernel(
    const uint32_t* __restrict__ bins, uint32_t* __restrict__ cursor) {
  __shared__ uint32_t lds[1024];
  int t = threadIdx.x;
  uint32_t local[32];
  uint32_t s = 0;
  #pragma unroll
  for (int j = 0; j < 32; ++j) { local[j] = bins[t*32 + j]; s += local[j]; }
  lds[t] = s;
  __syncthreads();
  for (int off = 1; off < 1024; off <<= 1) {
    uint32_t v = (t >= off) ? lds[t - off] : 0u;
    __syncthreads();
    lds[t] += v;
    __syncthreads();
  }
  uint32_t run = lds[t] - s;
  #pragma unroll
  for (int j = 0; j < 32; ++j) { cursor[t*32 + j] = run; run += local[j]; }
}

// 1 pt/thread (R9-proven: 4096 blocks -> TLP hides atomic+store latency)
__global__ __launch_bounds__(256) void scatter_kernel(
    const float* __restrict__ positions, uint32_t* __restrict__ cursor,
    evu4* __restrict__ spi, int n) {
  int p = blockIdx.x * 256 + threadIdx.x;
  if (p >= n) return;
  float x = positions[3*p], y = positions[3*p+1], z = positions[3*p+2];
  uint32_t k = cell_key(x, y, z);
  uint32_t dst = atomicAdd(&cursor[k], 1u);
  evu4 v;
  v.x = __float_as_uint(x);
  v.y = __float_as_uint(y);
  v.z = __float_as_uint(z);
  v.w = (uint32_t)p;
  spi[dst] = v;
}

// ---------- per-point hashed-level feature (f16 table) ----------
__device__ __forceinline__ void hash_feat_h(
    float x01, float y01, float z01, float scale, uint32_t mask,
    const _Float16* __restrict__ tbl, float& f0, float& f1)
{
  float px = x01 * scale + 0.5f;
  float py = y01 * scale + 0.5f;
  float pz = z01 * scale + 0.5f;
  float fx = floorf(px), fy = floorf(py), fz = floorf(pz);
  float tx = px - fx, ty = py - fy, tz = pz - fz;
  uint32_t gx = (uint32_t)fx, gy = (uint32_t)fy, gz = (uint32_t)fz;

  float wxa = 1.0f - tx, wxb = tx;
  float wy_[2] = {1.0f - ty, ty};
  float wz_[2] = {1.0f - tz, tz};

  f0 = 0.0f; f1 = 0.0f;
  if ((gx & 1u) == 0u) {
    #pragma unroll
    for (int cyz = 0; cyz < 4; ++cyz) {
      uint32_t cy = gy + (cyz & 1u);
      uint32_t cz = gz + (cyz >> 1);
      uint32_t hy = (cy * 2654435761u) ^ (cz * 805459861u);
      uint32_t ha = (gx ^ hy) & mask;
      float wyz = wy_[cyz & 1u] * wz_[cyz >> 1];
      float wa = wxa * wyz, wb = wxb * wyz;
      // pair (ha&~1, ha|1): 8 B aligned f16x4 — one line, one instr
      const evh4 t4 = *reinterpret_cast<const evh4*>(tbl + 2u * (ha & ~1u));
      float ta0, ta1, tb0, tb1;
      if (ha & 1u) { ta0 = (float)t4.z; ta1 = (float)t4.w; tb0 = (float)t4.x; tb1 = (float)t4.y; }
      else         { ta0 = (float)t4.x; ta1 = (float)t4.y; tb0 = (float)t4.z; tb1 = (float)t4.w; }
      f0 += wa * ta0; f1 += wa * ta1;
      f0 += wb * tb0; f1 += wb * tb1;
    }
  } else {
    #pragma unroll
    for (int cyz = 0; cyz < 4; ++cyz) {
      uint32_t cy = gy + (cyz & 1u);
      uint32_t cz = gz + (cyz >> 1);
      uint32_t hy = (cy * 2654435761u) ^ (cz * 805459861u);
      uint32_t ha = (gx ^ hy) & mask;
      uint32_t hb = ((gx + 1u) ^ hy) & mask;
      float wyz = wy_[cyz & 1u] * wz_[cyz >> 1];
      float wa = wxa * wyz, wb = wxb * wyz;
      const evh2 ta = *reinterpret_cast<const evh2*>(tbl + 2u * ha);
      const evh2 tb = *reinterpret_cast<const evh2*>(tbl + 2u * hb);
      f0 += wa * (float)ta.x; f1 += wa * (float)ta.y;
      f0 += wb * (float)tb.x; f1 += wb * (float)tb.y;
    }
  }
}

// ---------- merged hashed levels 6..11 (coarse; hot windows << L2) ----------
__global__ __launch_bounds__(256) void hash_multi_kernel(
    const evu4* __restrict__ spi,
    const _Float16* __restrict__ tableH,
    evh2* __restrict__ tmpH,            // slots 0..5 <- levels 6..11
    ParamsH ph, uint32_t mask, int n)
{
  int bid = xcd_swz(blockIdx.x, gridDim.x);
  int t = bid * 256 + threadIdx.x;
  int p0 = t * 2;
  if (p0 >= n) return;

  evu4 a = __builtin_nontemporal_load(spi + p0);
  evu4 b = __builtin_nontemporal_load(spi + p0 + 1);
  float x0 = (__uint_as_float(a.x) + 1.0f) * 0.5f;
  float y0 = (__uint_as_float(a.y) + 1.0f) * 0.5f;
  float z0 = (__uint_as_float(a.z) + 1.0f) * 0.5f;
  float x1 = (__uint_as_float(b.x) + 1.0f) * 0.5f;
  float y1 = (__uint_as_float(b.y) + 1.0f) * 0.5f;
  float z1 = (__uint_as_float(b.z) + 1.0f) * 0.5f;

  #pragma unroll
  for (int l = 0; l < NMERGE; ++l) {
    const float s = ph.scale[l];
    const _Float16* __restrict__ tbl = tableH + 2u * ph.offset[l];
    float f00, f01, f10, f11;
    hash_feat_h(x0, y0, z0, s, mask, tbl, f00, f01);
    hash_feat_h(x1, y1, z1, s, mask, tbl, f10, f11);
    evh4 v;
    v.x = (_Float16)f00; v.y = (_Float16)f01;
    v.z = (_Float16)f10; v.w = (_Float16)f11;
    __builtin_nontemporal_store(v,
        reinterpret_cast<evh4*>(tmpH + (size_t)l * n + p0));
  }
}

// ---------- pair of fine hashed levels: 2 x 2 MB f16 tables = 4 MB = per-XCD L2
// (R14 lesson applied: merge only while combined hot footprint fits L2) ----------
__global__ __launch_bounds__(256) void hash_pair_kernel(
    const evu4* __restrict__ spi,
    const _Float16* __restrict__ tableH,
    evh2* __restrict__ tmpH,
    ParamsP pp, uint32_t mask, int slotBase, int n)
{
  int bid = xcd_swz(blockIdx.x, gridDim.x);
  int t = bid * 256 + threadIdx.x;
  int p0 = t * 2;
  if (p0 >= n) return;

  evu4 a = __builtin_nontemporal_load(spi + p0);
  evu4 b = __builtin_nontemporal_load(spi + p0 + 1);
  float x0 = (__uint_as_float(a.x) + 1.0f) * 0.5f;
  float y0 = (__uint_as_float(a.y) + 1.0f) * 0.5f;
  float z0 = (__uint_as_float(a.z) + 1.0f) * 0.5f;
  float x1 = (__uint_as_float(b.x) + 1.0f) * 0.5f;
  float y1 = (__uint_as_float(b.y) + 1.0f) * 0.5f;
  float z1 = (__uint_as_float(b.z) + 1.0f) * 0.5f;

  #pragma unroll
  for (int l = 0; l < 2; ++l) {
    const float s = pp.scale[l];
    const _Float16* __restrict__ tbl = tableH + 2u * pp.offset[l];
    float f00, f01, f10, f11;
    hash_feat_h(x0, y0, z0, s, mask, tbl, f00, f01);
    hash_feat_h(x1, y1, z1, s, mask, tbl, f10, f11);
    evh4 v;
    v.x = (_Float16)f00; v.y = (_Float16)f01;
    v.z = (_Float16)f10; v.w = (_Float16)f11;
    __builtin_nontemporal_store(v,
        reinterpret_cast<evh4*>(tmpH + (size_t)(slotBase + l) * n + p0));
  }
}

// ---------- fused: dense gathers (f16 tables) + hash tmps + un-sort pack ----------
#define PBS 128
__global__ __launch_bounds__(PBS) void dense_pack2_kernel(
    const evu4* __restrict__ spi,
    const _Float16* __restrict__ tableH,
    const evh2* __restrict__ tmpH,      // [NHASH][n] half2, sorted space
    float* __restrict__ out,
    ParamsD prm, int n)
{
  __shared__ float lds[PBS * 33];
  __shared__ uint32_t lds_oi[PBS];
  int t = threadIdx.x;
  int base = xcd_swz(blockIdx.x, gridDim.x) * PBS;
  int p = base + t;

  if (p < n) {
    evu4 a = __builtin_nontemporal_load(spi + p);
    float x = (__uint_as_float(a.x) + 1.0f) * 0.5f;
    float y = (__uint_as_float(a.y) + 1.0f) * 0.5f;
    float z = (__uint_as_float(a.z) + 1.0f) * 0.5f;
    lds_oi[t] = a.w;

    #pragma unroll
    for (int l = 0; l < NDENSE; ++l) {
      const float s = prm.scale[l];
      const uint32_t res = prm.res[l];
      const uint32_t ms = prm.msize[l];
      const _Float16* __restrict__ tbl = tableH + 2u * prm.offset[l];
      const uint32_t res2 = res * res;

      float px = x * s + 0.5f;
      float py = y * s + 0.5f;
      float pz = z * s + 0.5f;
      float fx = floorf(px), fy = floorf(py), fz = floorf(pz);
      float tx = px - fx, ty = py - fy, tz = pz - fz;
      uint32_t gx = (uint32_t)fx, gy = (uint32_t)fy, gz = (uint32_t)fz;

      float wxa = 1.0f - tx, wxb = tx;
      float wy_[2] = {1.0f - ty, ty};
      float wz_[2] = {1.0f - tz, tz};

      float f0 = 0.0f, f1 = 0.0f;
      #pragma unroll
      for (int cyz = 0; cyz < 4; ++cyz) {
        uint32_t cy = gy + (cyz & 1u);
        uint32_t cz = gz + ((cyz >> 1) & 1u);
        uint32_t h = gx + cy * res + cz * res2;   // raw in [0, 2*ms)
        if (h >= ms) h -= ms;
        float wyz = wy_[cyz & 1u] * wz_[(cyz >> 1) & 1u];
        uint32_t hb = (h + 1u < ms) ? (h + 1u) : 0u;   // b wraps at ms-1
        const evh2 ta = *reinterpret_cast<const evh2*>(tbl + 2u * h);
        const evh2 tb = *reinterpret_cast<const evh2*>(tbl + 2u * hb);
        float wa = wxa * wyz, wb = wxb * wyz;
        f0 += wa * (float)ta.x; f1 += wa * (float)ta.y;
        f0 += wb * (float)tb.x; f1 += wb * (float)tb.y;
      }
      lds[t*33 + 2*l]     = f0;
      lds[t*33 + 2*l + 1] = f1;
    }

    #pragma unroll
    for (int j = 0; j < NHASH; ++j) {
      evh2 v = __builtin_nontemporal_load(tmpH + (size_t)j * n + p);
      lds[t*33 + 12 + 2*j]     = (float)v.x;
      lds[t*33 + 12 + 2*j + 1] = (float)v.y;
    }
  }
  __syncthreads();

  if (base + PBS <= n) {
    // per instruction each WAVE writes 8 complete 128-B lines -> nt is safe
    int qr = t >> 3, r = t & 7;
    #pragma unroll
    for (int k = 0; k < 8; ++k) {
      int q = k * (PBS/8) + qr;
      uint32_t oi = lds_oi[q];
      evf4 v;
      v.x = lds[q*33 + r*4];     v.y = lds[q*33 + r*4 + 1];
      v.z = lds[q*33 + r*4 + 2]; v.w = lds[q*33 + r*4 + 3];
      __builtin_nontemporal_store(v,
          reinterpret_cast<evf4*>(out + (size_t)oi * 32u) + r);
    }
  } else if (p < n) {
    uint32_t oi = lds_oi[t];
    float4* o = reinterpret_cast<float4*>(out + (size_t)oi * 32u);
    #pragma unroll
    for (int k = 0; k < 8; ++k)
      o[k] = make_float4(lds[t*33 + 4*k], lds[t*33 + 4*k + 1],
                         lds[t*33 + 4*k + 2], lds[t*33 + 4*k + 3]);
  }
}

// ---------- last-resort fallback: single fused kernel (f32 table, no ws) ----------
__global__ __launch_bounds__(256) void hash_enc_kernel(
    const float* __restrict__ positions,
    const float* __restrict__ table,
    float* __restrict__ out,
    Params prm, int n)
{
  int p = blockIdx.x * 256 + threadIdx.x;
  if (p >= n) return;

  float x = (positions[3*p+0] + 1.0f) * 0.5f;
  float y = (positions[3*p+1] + 1.0f) * 0.5f;
  float z = (positions[3*p+2] + 1.0f) * 0.5f;

  float acc[32];

  #pragma unroll
  for (int l = 0; l < NLV; ++l) {
    const float s = prm.scale[l];
    const uint32_t res = prm.res[l];
    const uint32_t ms = prm.msize[l];
    const uint32_t off = prm.offset[l];
    float px = x * s + 0.5f;
    float py = y * s + 0.5f;
    float pz = z * s + 0.5f;
    float fx = floorf(px), fy = floorf(py), fz = floorf(pz);
    float tx = px - fx, ty = py - fy, tz = pz - fz;
    uint32_t gx = (uint32_t)fx, gy = (uint32_t)fy, gz = (uint32_t)fz;
    float wx[2] = {1.0f - tx, tx};
    float wy[2] = {1.0f - ty, ty};
    float wz[2] = {1.0f - tz, tz};
    float f0 = 0.0f, f1 = 0.0f;
    #pragma unroll
    for (int c = 0; c < 8; ++c) {
      uint32_t cx = gx + (c & 1u);
      uint32_t cy = gy + ((c >> 1) & 1u);
      uint32_t cz = gz + ((c >> 2) & 1u);
      uint32_t h;
      if (l < NDENSE) {
        h = cx + cy * res + cz * res * res;
        if (h >= ms) h -= ms;
      } else {
        h = cx ^ (cy * 2654435761u) ^ (cz * 805459861u);
        h &= (ms - 1u);
      }
      float w = (wx[c & 1u] * wy[(c >> 1) & 1u]) * wz[(c >> 2) & 1u];
      const float2 t = *reinterpret_cast<const float2*>(table + 2u * (h + off));
      f0 += w * t.x;
      f1 += w * t.y;
    }
    acc[2*l]   = f0;
    acc[2*l+1] = f1;
  }

  float4* o = reinterpret_cast<float4*>(out + (size_t)p * 32u);
  #pragma unroll
  for (int k = 0; k < 8; ++k)
    o[k] = make_float4(acc[4*k+0], acc[4*k+1], acc[4*k+2], acc[4*k+3]);
}

extern "C" void kernel_launch(void* const* d_in, const int* in_sizes, int n_in,
                              void* d_out, int out_size, void* d_ws, size_t ws_size,
                              hipStream_t stream) {
  const float* positions = (const float*)d_in[0];
  const float* table     = (const float*)d_in[1];
  float* out             = (float*)d_out;
  int n  = in_sizes[0] / 3;
  int nf = in_sizes[1];           // total table floats (11445040)

  // Level metadata, exactly mirroring the reference (f64 exp/log; f32 cast
  // for the encode-path scale; level 5 is dense with res=65 due to the
  // B_SCALE^5 = 4.0000007 float quirk).
  Params prm;
  const double lnb = log(1.3195079565048218);
  uint32_t off = 0;
  for (int l = 0; l < NLV; ++l) {
    double sd = 16.0 * exp((double)l * lnb) - 1.0;
    uint32_t res_meta = (uint32_t)ceil(sd) + 1u;
    uint64_t p3 = (uint64_t)res_meta * res_meta * res_meta;
    uint64_t ps = (p3 % 8ull) ? ((p3 + 7ull) / 8ull) * 8ull : p3;
    if (ps > (1ull << 19)) ps = 1ull << 19;
    float sf = (float)sd;
    uint32_t res_enc = (uint32_t)(ceilf(sf) + 1.0f);
    prm.scale[l]  = sf;
    prm.res[l]    = res_enc;
    prm.msize[l]  = (uint32_t)ps;
    prm.offset[l] = off;
    off += (uint32_t)ps;
  }
  ParamsD pd;
  for (int l = 0; l < NDENSE; ++l) {
    pd.scale[l] = prm.scale[l]; pd.res[l] = prm.res[l];
    pd.msize[l] = prm.msize[l]; pd.offset[l] = prm.offset[l];
  }
  ParamsH ph;
  for (int l = 0; l < NMERGE; ++l) {
    ph.scale[l]  = prm.scale[NDENSE + l];
    ph.offset[l] = prm.offset[NDENSE + l];
  }
  ParamsP pp12, pp14;
  pp12.scale[0] = prm.scale[12]; pp12.offset[0] = prm.offset[12];
  pp12.scale[1] = prm.scale[13]; pp12.offset[1] = prm.offset[13];
  pp14.scale[0] = prm.scale[14]; pp14.offset[0] = prm.offset[14];
  pp14.scale[1] = prm.scale[15]; pp14.offset[1] = prm.offset[15];

  dim3 block(256);
  dim3 gfull((n + 255) / 256);
  dim3 ghash((n/2 + 255) / 256);
  dim3 gquad((n/4 + 255) / 256);
  dim3 gpack((n + PBS - 1) / PBS);
  dim3 gcvt((nf/4 + 255) / 256);

  // ws layout: [tmpH 10n*4][spi n*16][bins][cursor][tableH nf*2]
  size_t tmp_b  = (size_t)NHASH * n * sizeof(evh2);
  size_t sp_off = tmp_b;
  size_t bn_off = sp_off + (size_t)n * sizeof(evu4);
  size_t cu_off = bn_off + (size_t)NBINS * sizeof(uint32_t);
  size_t th_off = cu_off + (size_t)NBINS * sizeof(uint32_t);
  size_t total  = th_off + (size_t)nf * sizeof(_Float16);

  char* wsb = (char*)d_ws;

  if (ws_size >= total && (n % 4) == 0 && (nf % 4) == 0) {
    // ---- sorted path, f16 tables ----
    evh2*      tmpH   = (evh2*)wsb;
    evu4*      spi    = (evu4*)(wsb + sp_off);
    uint32_t*  bins   = (uint32_t*)(wsb + bn_off);
    uint32_t*  cursor = (uint32_t*)(wsb + cu_off);
    _Float16*  tableH = (_Float16*)(wsb + th_off);

    hipLaunchKernelGGL(cvt_kernel, gcvt, block, 0, stream, table, tableH, nf);
    hipLaunchKernelGGL(zero_bins_kernel, dim3((NBINS + 255) / 256), block, 0, stream, bins);
    hipLaunchKernelGGL(hist_kernel, gquad, block, 0, stream, positions, bins, n);
    hipLaunchKernelGGL(scan_kernel, dim3(1), dim3(1024), 0, stream, bins, cursor);
    hipLaunchKernelGGL(scatter_kernel, gfull, block, 0, stream,
                       positions, cursor, spi, n);

    // coarse levels 6..11 merged; fine levels merged in PAIRS (2x2MB = L2)
    hipLaunchKernelGGL(hash_multi_kernel, ghash, block, 0, stream,
                       spi, tableH, tmpH, ph, prm.msize[NDENSE] - 1u, n);
    hipLaunchKernelGGL(hash_pair_kernel, ghash, block, 0, stream,
                       spi, tableH, tmpH, pp12, prm.msize[NDENSE] - 1u, 6, n);
    hipLaunchKernelGGL(hash_pair_kernel, ghash, block, 0, stream,
                       spi, tableH, tmpH, pp14, prm.msize[NDENSE] - 1u, 8, n);
    hipLaunchKernelGGL(dense_pack2_kernel, gpack, dim3(PBS), 0, stream,
                       spi, tableH, tmpH, out, pd, n);
  } else {
    // fallback: correct single-kernel path (f32 table, no ws)
    hipLaunchKernelGGL(hash_enc_kernel, gfull, block, 0, stream,
                       positions, table, out, prm, n);
  }
}

// Round 17
// 390.178 us; speedup vs baseline: 1.2840x; 1.0055x over previous
//
#include <hip/hip_runtime.h>
#include <math.h>
#include <stdint.h>

#define NLV 16
#define NDENSE 6
#define NHASH 10
#define NMERGE 6          // hashed levels 6..11 merged (coarse: window-local)
#define SORT_RES 32
#define NBINS (SORT_RES * SORT_RES * SORT_RES)   // 32768

typedef float evf2 __attribute__((ext_vector_type(2)));
typedef float evf4 __attribute__((ext_vector_type(4)));
typedef unsigned int evu4 __attribute__((ext_vector_type(4)));
typedef _Float16 evh2 __attribute__((ext_vector_type(2)));
typedef _Float16 evh4 __attribute__((ext_vector_type(4)));

struct Params {
  float scale[NLV];
  uint32_t res[NLV];
  uint32_t msize[NLV];
  uint32_t offset[NLV];
};

struct ParamsD {
  float scale[NDENSE];
  uint32_t res[NDENSE];
  uint32_t msize[NDENSE];
  uint32_t offset[NDENSE];
};

struct ParamsH {
  float scale[NMERGE];
  uint32_t offset[NMERGE];
};

struct ParamsP {          // one pair of fine hashed levels
  float scale[2];
  uint32_t offset[2];
};

// bijective XCD swizzle (m204)
__device__ __forceinline__ int xcd_swz(int bid, int nwg) {
  int q = nwg >> 3, r = nwg & 7;
  int x = bid & 7, i = bid >> 3;
  return (x < r ? x * (q + 1) : r * (q + 1) + (x - r) * q) + i;
}

__device__ __forceinline__ uint32_t cell_key(float xr, float yr, float zr) {
  float x01 = (xr + 1.0f) * 0.5f;
  float y01 = (yr + 1.0f) * 0.5f;
  float z01 = (zr + 1.0f) * 0.5f;
  int cx = (int)(x01 * (float)SORT_RES);
  int cy = (int)(y01 * (float)SORT_RES);
  int cz = (int)(z01 * (float)SORT_RES);
  cx = cx < 0 ? 0 : (cx > SORT_RES-1 ? SORT_RES-1 : cx);
  cy = cy < 0 ? 0 : (cy > SORT_RES-1 ? SORT_RES-1 : cy);
  cz = cz < 0 ? 0 : (cz > SORT_RES-1 ? SORT_RES-1 : cz);
  return (uint32_t)(cx | (cy << 5) | (cz << 10));
}

// ---------------- f32 -> f16 table conversion (once; ~23 MB result) ----------------
__global__ __launch_bounds__(256) void cvt_kernel(
    const float* __restrict__ src, _Float16* __restrict__ dst, int nf) {
  int i4 = (blockIdx.x * 256 + threadIdx.x) * 4;
  if (i4 >= nf) return;
  const float4 v = *reinterpret_cast<const float4*>(src + i4);
  evh4 h;
  h.x = (_Float16)v.x; h.y = (_Float16)v.y;
  h.z = (_Float16)v.z; h.w = (_Float16)v.w;
  __builtin_nontemporal_store(h, reinterpret_cast<evh4*>(dst + i4));
}

// ---------------- sort machinery ----------------
__global__ __launch_bounds__(256) void zero_bins_kernel(uint32_t* bins) {
  int i = blockIdx.x * 256 + threadIdx.x;
  if (i < NBINS) bins[i] = 0u;
}

// 1 pt/thread (same TLP lesson as scatter: serialized atomic chains throttle)
__global__ __launch_bounds__(256) void hist_kernel(
    const float* __restrict__ positions, uint32_t* __restrict__ bins, int n) {
  int p = blockIdx.x * 256 + threadIdx.x;
  if (p >= n) return;
  float x = positions[3*p], y = positions[3*p+1], z = positions[3*p+2];
  atomicAdd(&bins[cell_key(x, y, z)], 1u);
}

__global__ __launch_bounds__(1024) void scan_kernel(
    const uint32_t* __restrict__ bins, uint32_t* __restrict__ cursor) {
  __shared__ uint32_t lds[1024];
  int t = threadIdx.x;
  uint32_t local[32];
  uint32_t s = 0;
  #pragma unroll
  for (int j = 0; j < 32; ++j) { local[j] = bins[t*32 + j]; s += local[j]; }
  lds[t] = s;
  __syncthreads();
  for (int off = 1; off < 1024; off <<= 1) {
    uint32_t v = (t >= off) ? lds[t - off] : 0u;
    __syncthreads();
    lds[t] += v;
    __syncthreads();
  }
  uint32_t run = lds[t] - s;
  #pragma unroll
  for (int j = 0; j < 32; ++j) { cursor[t*32 + j] = run; run += local[j]; }
}

// 1 pt/thread (R9-proven: 4096 blocks -> TLP hides atomic+store latency)
__global__ __launch_bounds__(256) void scatter_kernel(
    const float* __restrict__ positions, uint32_t* __restrict__ cursor,
    evu4* __restrict__ spi, int n) {
  int p = blockIdx.x * 256 + threadIdx.x;
  if (p >= n) return;
  float x = positions[3*p], y = positions[3*p+1], z = positions[3*p+2];
  uint32_t k = cell_key(x, y, z);
  uint32_t dst = atomicAdd(&cursor[k], 1u);
  evu4 v;
  v.x = __float_as_uint(x);
  v.y = __float_as_uint(y);
  v.z = __float_as_uint(z);
  v.w = (uint32_t)p;
  spi[dst] = v;
}

// ---------- per-point hashed-level feature (f16 table) ----------
__device__ __forceinline__ void hash_feat_h(
    float x01, float y01, float z01, float scale, uint32_t mask,
    const _Float16* __restrict__ tbl, float& f0, float& f1)
{
  float px = x01 * scale + 0.5f;
  float py = y01 * scale + 0.5f;
  float pz = z01 * scale + 0.5f;
  float fx = floorf(px), fy = floorf(py), fz = floorf(pz);
  float tx = px - fx, ty = py - fy, tz = pz - fz;
  uint32_t gx = (uint32_t)fx, gy = (uint32_t)fy, gz = (uint32_t)fz;

  float wxa = 1.0f - tx, wxb = tx;
  float wy_[2] = {1.0f - ty, ty};
  float wz_[2] = {1.0f - tz, tz};

  f0 = 0.0f; f1 = 0.0f;
  if ((gx & 1u) == 0u) {
    #pragma unroll
    for (int cyz = 0; cyz < 4; ++cyz) {
      uint32_t cy = gy + (cyz & 1u);
      uint32_t cz = gz + (cyz >> 1);
      uint32_t hy = (cy * 2654435761u) ^ (cz * 805459861u);
      uint32_t ha = (gx ^ hy) & mask;
      float wyz = wy_[cyz & 1u] * wz_[cyz >> 1];
      float wa = wxa * wyz, wb = wxb * wyz;
      // pair (ha&~1, ha|1): 8 B aligned f16x4 — one line, one instr
      const evh4 t4 = *reinterpret_cast<const evh4*>(tbl + 2u * (ha & ~1u));
      float ta0, ta1, tb0, tb1;
      if (ha & 1u) { ta0 = (float)t4.z; ta1 = (float)t4.w; tb0 = (float)t4.x; tb1 = (float)t4.y; }
      else         { ta0 = (float)t4.x; ta1 = (float)t4.y; tb0 = (float)t4.z; tb1 = (float)t4.w; }
      f0 += wa * ta0; f1 += wa * ta1;
      f0 += wb * tb0; f1 += wb * tb1;
    }
  } else {
    #pragma unroll
    for (int cyz = 0; cyz < 4; ++cyz) {
      uint32_t cy = gy + (cyz & 1u);
      uint32_t cz = gz + (cyz >> 1);
      uint32_t hy = (cy * 2654435761u) ^ (cz * 805459861u);
      uint32_t ha = (gx ^ hy) & mask;
      uint32_t hb = ((gx + 1u) ^ hy) & mask;
      float wyz = wy_[cyz & 1u] * wz_[cyz >> 1];
      float wa = wxa * wyz, wb = wxb * wyz;
      const evh2 ta = *reinterpret_cast<const evh2*>(tbl + 2u * ha);
      const evh2 tb = *reinterpret_cast<const evh2*>(tbl + 2u * hb);
      f0 += wa * (float)ta.x; f1 += wa * (float)ta.y;
      f0 += wb * (float)tb.x; f1 += wb * (float)tb.y;
    }
  }
}

// ---------- merged hashed levels 6..11 (coarse; hot windows << L2) ----------
__global__ __launch_bounds__(256) void hash_multi_kernel(
    const evu4* __restrict__ spi,
    const _Float16* __restrict__ tableH,
    evh2* __restrict__ tmpH,            // slots 0..5 <- levels 6..11
    ParamsH ph, uint32_t mask, int n)
{
  int bid = xcd_swz(blockIdx.x, gridDim.x);
  int t = bid * 256 + threadIdx.x;
  int p0 = t * 2;
  if (p0 >= n) return;

  evu4 a = __builtin_nontemporal_load(spi + p0);
  evu4 b = __builtin_nontemporal_load(spi + p0 + 1);
  float x0 = (__uint_as_float(a.x) + 1.0f) * 0.5f;
  float y0 = (__uint_as_float(a.y) + 1.0f) * 0.5f;
  float z0 = (__uint_as_float(a.z) + 1.0f) * 0.5f;
  float x1 = (__uint_as_float(b.x) + 1.0f) * 0.5f;
  float y1 = (__uint_as_float(b.y) + 1.0f) * 0.5f;
  float z1 = (__uint_as_float(b.z) + 1.0f) * 0.5f;

  #pragma unroll
  for (int l = 0; l < NMERGE; ++l) {
    const float s = ph.scale[l];
    const _Float16* __restrict__ tbl = tableH + 2u * ph.offset[l];
    float f00, f01, f10, f11;
    hash_feat_h(x0, y0, z0, s, mask, tbl, f00, f01);
    hash_feat_h(x1, y1, z1, s, mask, tbl, f10, f11);
    evh4 v;
    v.x = (_Float16)f00; v.y = (_Float16)f01;
    v.z = (_Float16)f10; v.w = (_Float16)f11;
    __builtin_nontemporal_store(v,
        reinterpret_cast<evh4*>(tmpH + (size_t)l * n + p0));
  }
}

// ---------- pair of fine hashed levels: 2 x 2 MB f16 tables = 4 MB = per-XCD L2 ----------
__global__ __launch_bounds__(256) void hash_pair_kernel(
    const evu4* __restrict__ spi,
    const _Float16* __restrict__ tableH,
    evh2* __restrict__ tmpH,
    ParamsP pp, uint32_t mask, int slotBase, int n)
{
  int bid = xcd_swz(blockIdx.x, gridDim.x);
  int t = bid * 256 + threadIdx.x;
  int p0 = t * 2;
  if (p0 >= n) return;

  evu4 a = __builtin_nontemporal_load(spi + p0);
  evu4 b = __builtin_nontemporal_load(spi + p0 + 1);
  float x0 = (__uint_as_float(a.x) + 1.0f) * 0.5f;
  float y0 = (__uint_as_float(a.y) + 1.0f) * 0.5f;
  float z0 = (__uint_as_float(a.z) + 1.0f) * 0.5f;
  float x1 = (__uint_as_float(b.x) + 1.0f) * 0.5f;
  float y1 = (__uint_as_float(b.y) + 1.0f) * 0.5f;
  float z1 = (__uint_as_float(b.z) + 1.0f) * 0.5f;

  #pragma unroll
  for (int l = 0; l < 2; ++l) {
    const float s = pp.scale[l];
    const _Float16* __restrict__ tbl = tableH + 2u * pp.offset[l];
    float f00, f01, f10, f11;
    hash_feat_h(x0, y0, z0, s, mask, tbl, f00, f01);
    hash_feat_h(x1, y1, z1, s, mask, tbl, f10, f11);
    evh4 v;
    v.x = (_Float16)f00; v.y = (_Float16)f01;
    v.z = (_Float16)f10; v.w = (_Float16)f11;
    __builtin_nontemporal_store(v,
        reinterpret_cast<evh4*>(tmpH + (size_t)(slotBase + l) * n + p0));
  }
}

// ---------- fused: dense gathers (f16 tables) + hash tmps + un-sort pack ----------
#define PBS 256
__global__ __launch_bounds__(PBS) void dense_pack2_kernel(
    const evu4* __restrict__ spi,
    const _Float16* __restrict__ tableH,
    const evh2* __restrict__ tmpH,      // [NHASH][n] half2, sorted space
    float* __restrict__ out,
    ParamsD prm, int n)
{
  __shared__ float lds[PBS * 33];       // 33.8 KB -> 4 blocks/CU
  __shared__ uint32_t lds_oi[PBS];
  int t = threadIdx.x;
  int base = xcd_swz(blockIdx.x, gridDim.x) * PBS;
  int p = base + t;

  if (p < n) {
    evu4 a = __builtin_nontemporal_load(spi + p);
    float x = (__uint_as_float(a.x) + 1.0f) * 0.5f;
    float y = (__uint_as_float(a.y) + 1.0f) * 0.5f;
    float z = (__uint_as_float(a.z) + 1.0f) * 0.5f;
    lds_oi[t] = a.w;

    #pragma unroll
    for (int l = 0; l < NDENSE; ++l) {
      const float s = prm.scale[l];
      const uint32_t res = prm.res[l];
      const uint32_t ms = prm.msize[l];
      const _Float16* __restrict__ tbl = tableH + 2u * prm.offset[l];
      const uint32_t res2 = res * res;

      float px = x * s + 0.5f;
      float py = y * s + 0.5f;
      float pz = z * s + 0.5f;
      float fx = floorf(px), fy = floorf(py), fz = floorf(pz);
      float tx = px - fx, ty = py - fy, tz = pz - fz;
      uint32_t gx = (uint32_t)fx, gy = (uint32_t)fy, gz = (uint32_t)fz;

      float wxa = 1.0f - tx, wxb = tx;
      float wy_[2] = {1.0f - ty, ty};
      float wz_[2] = {1.0f - tz, tz};

      float f0 = 0.0f, f1 = 0.0f;
      #pragma unroll
      for (int cyz = 0; cyz < 4; ++cyz) {
        uint32_t cy = gy + (cyz & 1u);
        uint32_t cz = gz + ((cyz >> 1) & 1u);
        uint32_t h = gx + cy * res + cz * res2;   // raw in [0, 2*ms)
        if (h >= ms) h -= ms;
        float wyz = wy_[cyz & 1u] * wz_[(cyz >> 1) & 1u];
        uint32_t hb = (h + 1u < ms) ? (h + 1u) : 0u;   // b wraps at ms-1
        const evh2 ta = *reinterpret_cast<const evh2*>(tbl + 2u * h);
        const evh2 tb = *reinterpret_cast<const evh2*>(tbl + 2u * hb);
        float wa = wxa * wyz, wb = wxb * wyz;
        f0 += wa * (float)ta.x; f1 += wa * (float)ta.y;
        f0 += wb * (float)tb.x; f1 += wb * (float)tb.y;
      }
      lds[t*33 + 2*l]     = f0;
      lds[t*33 + 2*l + 1] = f1;
    }

    #pragma unroll
    for (int j = 0; j < NHASH; ++j) {
      evh2 v = __builtin_nontemporal_load(tmpH + (size_t)j * n + p);
      lds[t*33 + 12 + 2*j]     = (float)v.x;
      lds[t*33 + 12 + 2*j + 1] = (float)v.y;
    }
  }
  __syncthreads();

  if (base + PBS <= n) {
    // per instruction each WAVE writes 8 complete 128-B lines -> nt is safe
    int qr = t >> 3, r = t & 7;                   // qr in [0,32), r in [0,8)
    #pragma unroll
    for (int k = 0; k < 8; ++k) {
      int q = k * (PBS/8) + qr;
      uint32_t oi = lds_oi[q];
      evf4 v;
      v.x = lds[q*33 + r*4];     v.y = lds[q*33 + r*4 + 1];
      v.z = lds[q*33 + r*4 + 2]; v.w = lds[q*33 + r*4 + 3];
      __builtin_nontemporal_store(v,
          reinterpret_cast<evf4*>(out + (size_t)oi * 32u) + r);
    }
  } else if (p < n) {
    uint32_t oi = lds_oi[t];
    float4* o = reinterpret_cast<float4*>(out + (size_t)oi * 32u);
    #pragma unroll
    for (int k = 0; k < 8; ++k)
      o[k] = make_float4(lds[t*33 + 4*k], lds[t*33 + 4*k + 1],
                         lds[t*33 + 4*k + 2], lds[t*33 + 4*k + 3]);
  }
}

// ---------- last-resort fallback: single fused kernel (f32 table, no ws) ----------
__global__ __launch_bounds__(256) void hash_enc_kernel(
    const float* __restrict__ positions,
    const float* __restrict__ table,
    float* __restrict__ out,
    Params prm, int n)
{
  int p = blockIdx.x * 256 + threadIdx.x;
  if (p >= n) return;

  float x = (positions[3*p+0] + 1.0f) * 0.5f;
  float y = (positions[3*p+1] + 1.0f) * 0.5f;
  float z = (positions[3*p+2] + 1.0f) * 0.5f;

  float acc[32];

  #pragma unroll
  for (int l = 0; l < NLV; ++l) {
    const float s = prm.scale[l];
    const uint32_t res = prm.res[l];
    const uint32_t ms = prm.msize[l];
    const uint32_t off = prm.offset[l];
    float px = x * s + 0.5f;
    float py = y * s + 0.5f;
    float pz = z * s + 0.5f;
    float fx = floorf(px), fy = floorf(py), fz = floorf(pz);
    float tx = px - fx, ty = py - fy, tz = pz - fz;
    uint32_t gx = (uint32_t)fx, gy = (uint32_t)fy, gz = (uint32_t)fz;
    float wx[2] = {1.0f - tx, tx};
    float wy[2] = {1.0f - ty, ty};
    float wz[2] = {1.0f - tz, tz};
    float f0 = 0.0f, f1 = 0.0f;
    #pragma unroll
    for (int c = 0; c < 8; ++c) {
      uint32_t cx = gx + (c & 1u);
      uint32_t cy = gy + ((c >> 1) & 1u);
      uint32_t cz = gz + ((c >> 2) & 1u);
      uint32_t h;
      if (l < NDENSE) {
        h = cx + cy * res + cz * res * res;
        if (h >= ms) h -= ms;
      } else {
        h = cx ^ (cy * 2654435761u) ^ (cz * 805459861u);
        h &= (ms - 1u);
      }
      float w = (wx[c & 1u] * wy[(c >> 1) & 1u]) * wz[(c >> 2) & 1u];
      const float2 t = *reinterpret_cast<const float2*>(table + 2u * (h + off));
      f0 += w * t.x;
      f1 += w * t.y;
    }
    acc[2*l]   = f0;
    acc[2*l+1] = f1;
  }

  float4* o = reinterpret_cast<float4*>(out + (size_t)p * 32u);
  #pragma unroll
  for (int k = 0; k < 8; ++k)
    o[k] = make_float4(acc[4*k+0], acc[4*k+1], acc[4*k+2], acc[4*k+3]);
}

extern "C" void kernel_launch(void* const* d_in, const int* in_sizes, int n_in,
                              void* d_out, int out_size, void* d_ws, size_t ws_size,
                              hipStream_t stream) {
  const float* positions = (const float*)d_in[0];
  const float* table     = (const float*)d_in[1];
  float* out             = (float*)d_out;
  int n  = in_sizes[0] / 3;
  int nf = in_sizes[1];           // total table floats (11445040)

  // Level metadata, exactly mirroring the reference (f64 exp/log; f32 cast
  // for the encode-path scale; level 5 is dense with res=65 due to the
  // B_SCALE^5 = 4.0000007 float quirk).
  Params prm;
  const double lnb = log(1.3195079565048218);
  uint32_t off = 0;
  for (int l = 0; l < NLV; ++l) {
    double sd = 16.0 * exp((double)l * lnb) - 1.0;
    uint32_t res_meta = (uint32_t)ceil(sd) + 1u;
    uint64_t p3 = (uint64_t)res_meta * res_meta * res_meta;
    uint64_t ps = (p3 % 8ull) ? ((p3 + 7ull) / 8ull) * 8ull : p3;
    if (ps > (1ull << 19)) ps = 1ull << 19;
    float sf = (float)sd;
    uint32_t res_enc = (uint32_t)(ceilf(sf) + 1.0f);
    prm.scale[l]  = sf;
    prm.res[l]    = res_enc;
    prm.msize[l]  = (uint32_t)ps;
    prm.offset[l] = off;
    off += (uint32_t)ps;
  }
  ParamsD pd;
  for (int l = 0; l < NDENSE; ++l) {
    pd.scale[l] = prm.scale[l]; pd.res[l] = prm.res[l];
    pd.msize[l] = prm.msize[l]; pd.offset[l] = prm.offset[l];
  }
  ParamsH ph;
  for (int l = 0; l < NMERGE; ++l) {
    ph.scale[l]  = prm.scale[NDENSE + l];
    ph.offset[l] = prm.offset[NDENSE + l];
  }
  ParamsP pp12, pp14;
  pp12.scale[0] = prm.scale[12]; pp12.offset[0] = prm.offset[12];
  pp12.scale[1] = prm.scale[13]; pp12.offset[1] = prm.offset[13];
  pp14.scale[0] = prm.scale[14]; pp14.offset[0] = prm.offset[14];
  pp14.scale[1] = prm.scale[15]; pp14.offset[1] = prm.offset[15];

  dim3 block(256);
  dim3 gfull((n + 255) / 256);
  dim3 ghash((n/2 + 255) / 256);
  dim3 gpack((n + PBS - 1) / PBS);
  dim3 gcvt((nf/4 + 255) / 256);

  // ws layout: [tmpH 10n*4][spi n*16][bins][cursor][tableH nf*2]
  size_t tmp_b  = (size_t)NHASH * n * sizeof(evh2);
  size_t sp_off = tmp_b;
  size_t bn_off = sp_off + (size_t)n * sizeof(evu4);
  size_t cu_off = bn_off + (size_t)NBINS * sizeof(uint32_t);
  size_t th_off = cu_off + (size_t)NBINS * sizeof(uint32_t);
  size_t total  = th_off + (size_t)nf * sizeof(_Float16);

  char* wsb = (char*)d_ws;

  if (ws_size >= total && (n % 4) == 0 && (nf % 4) == 0) {
    // ---- sorted path, f16 tables ----
    evh2*      tmpH   = (evh2*)wsb;
    evu4*      spi    = (evu4*)(wsb + sp_off);
    uint32_t*  bins   = (uint32_t*)(wsb + bn_off);
    uint32_t*  cursor = (uint32_t*)(wsb + cu_off);
    _Float16*  tableH = (_Float16*)(wsb + th_off);

    hipLaunchKernelGGL(cvt_kernel, gcvt, block, 0, stream, table, tableH, nf);
    hipLaunchKernelGGL(zero_bins_kernel, dim3((NBINS + 255) / 256), block, 0, stream, bins);
    hipLaunchKernelGGL(hist_kernel, gfull, block, 0, stream, positions, bins, n);
    hipLaunchKernelGGL(scan_kernel, dim3(1), dim3(1024), 0, stream, bins, cursor);
    hipLaunchKernelGGL(scatter_kernel, gfull, block, 0, stream,
                       positions, cursor, spi, n);

    // coarse levels 6..11 merged; fine levels merged in PAIRS (2x2MB = L2)
    hipLaunchKernelGGL(hash_multi_kernel, ghash, block, 0, stream,
                       spi, tableH, tmpH, ph, prm.msize[NDENSE] - 1u, n);
    hipLaunchKernelGGL(hash_pair_kernel, ghash, block, 0, stream,
                       spi, tableH, tmpH, pp12, prm.msize[NDENSE] - 1u, 6, n);
    hipLaunchKernelGGL(hash_pair_kernel, ghash, block, 0, stream,
                       spi, tableH, tmpH, pp14, prm.msize[NDENSE] - 1u, 8, n);
    hipLaunchKernelGGL(dense_pack2_kernel, gpack, dim3(PBS), 0, stream,
                       spi, tableH, tmpH, out, pd, n);
  } else {
    // fallback: correct single-kernel path (f32 table, no ws)
    hipLaunchKernelGGL(hash_enc_kernel, gfull, block, 0, stream,
                       positions, table, out, prm, n);
  }
}